// Round 1
// baseline (963.531 us; speedup 1.0000x reference)
//
#include <hip/hip_runtime.h>
#include <math.h>

// Problem constants (from reference)
#define BATCH 32
#define NH    16
#define HD    128
#define BS    16        // tokens per KV block
#define MAXB  128       // blocks per sequence
#define LMAX  (MAXB*BS) // 2048 max context
#define SCALE 0.08838834764831845f  // 1/sqrt(128)

// One workgroup per (b,h). 256 threads = 4 waves = 8 half-waves of 32 lanes.
// Half-wave i processes tokens t = i, i+8, i+16, ... Each lane loads float4
// (16B) of the token's 512B K/V vector -> fully coalesced.
__global__ __launch_bounds__(256) void paged_attn_kernel(
    const float* __restrict__ q,    // [B,H,D]
    const float* __restrict__ kc,   // [NB,BS,H,D]
    const float* __restrict__ vc,   // [NB,BS,H,D]
    const int*   __restrict__ bt,   // [B,MAXB]
    const int*   __restrict__ cl,   // [B]
    float*       __restrict__ out)  // [B,H,D]
{
    const int bh   = blockIdx.x;
    const int b    = bh >> 4;      // / NH
    const int h    = bh & (NH-1);
    const int tid  = threadIdx.x;
    const int l32  = tid & 31;     // lane within half-wave
    const int hw   = tid >> 5;     // half-wave id 0..7
    const int wave = tid >> 6;     // wave id 0..3
    const int lane = tid & 63;

    __shared__ float  s_scores[LMAX];   // 8 KB
    __shared__ float  s_part[4];
    __shared__ float  s_bcast;
    __shared__ int    s_blk[MAXB];      // 512 B
    __shared__ float4 s_acc[8][32];     // 4 KB

    const int ctx = cl[b];

    if (tid < MAXB) s_blk[tid] = bt[b * MAXB + tid];

    // Each half-wave holds the full q vector: lane l32 owns dims [4*l32, 4*l32+4)
    const float4 qv = ((const float4*)(q + (size_t)bh * HD))[l32];
    __syncthreads();

    // ---- Pass 1: scores[t] = SCALE * dot(q, K[t]) -> LDS ----
    #pragma unroll 4
    for (int t = hw; t < ctx; t += 8) {
        const int blk = s_blk[t >> 4];
        const float4 kv =
            ((const float4*)(kc + (((size_t)blk * BS + (t & (BS-1))) * NH + h) * HD))[l32];
        float d = qv.x*kv.x + qv.y*kv.y + qv.z*kv.z + qv.w*kv.w;
        // reduce over the 32-lane half (xor masks <=16 stay within each half)
        d += __shfl_xor(d, 16);
        d += __shfl_xor(d, 8);
        d += __shfl_xor(d, 4);
        d += __shfl_xor(d, 2);
        d += __shfl_xor(d, 1);
        if (l32 == 0) s_scores[t] = d * SCALE;
    }
    __syncthreads();

    // ---- Block max over scores ----
    float m = -INFINITY;
    for (int t = tid; t < ctx; t += 256) m = fmaxf(m, s_scores[t]);
    #pragma unroll
    for (int off = 32; off >= 1; off >>= 1) m = fmaxf(m, __shfl_xor(m, off));
    if (lane == 0) s_part[wave] = m;
    __syncthreads();
    if (tid == 0)
        s_bcast = fmaxf(fmaxf(s_part[0], s_part[1]), fmaxf(s_part[2], s_part[3]));
    __syncthreads();
    m = s_bcast;

    // ---- exp + block sum (each thread rewrites only its own elements) ----
    float lsum = 0.f;
    for (int t = tid; t < ctx; t += 256) {
        const float e = __expf(s_scores[t] - m);
        s_scores[t] = e;
        lsum += e;
    }
    #pragma unroll
    for (int off = 32; off >= 1; off >>= 1) lsum += __shfl_xor(lsum, off);
    __syncthreads();                 // everyone has read old s_bcast & s_part
    if (lane == 0) s_part[wave] = lsum;
    __syncthreads();
    if (tid == 0)
        s_bcast = (s_part[0] + s_part[1]) + (s_part[2] + s_part[3]);
    __syncthreads();                 // also publishes exp'd s_scores for pass 2

    // ---- Pass 2: out = sum_t p[t] * V[t] ----
    float4 acc = make_float4(0.f, 0.f, 0.f, 0.f);
    #pragma unroll 4
    for (int t = hw; t < ctx; t += 8) {
        const float p = s_scores[t];             // broadcast (no bank conflict)
        const int blk = s_blk[t >> 4];
        const float4 vv =
            ((const float4*)(vc + (((size_t)blk * BS + (t & (BS-1))) * NH + h) * HD))[l32];
        acc.x += p * vv.x;
        acc.y += p * vv.y;
        acc.z += p * vv.z;
        acc.w += p * vv.w;
    }
    s_acc[hw][l32] = acc;
    __syncthreads();

    if (tid < 32) {
        float4 r = s_acc[0][tid];
        #pragma unroll
        for (int i = 1; i < 8; i++) {
            const float4 a = s_acc[i][tid];
            r.x += a.x; r.y += a.y; r.z += a.z; r.w += a.w;
        }
        const float inv = 1.0f / s_bcast;
        r.x *= inv; r.y *= inv; r.z *= inv; r.w *= inv;
        ((float4*)(out + (size_t)bh * HD))[tid] = r;
    }
}

extern "C" void kernel_launch(void* const* d_in, const int* in_sizes, int n_in,
                              void* d_out, int out_size, void* d_ws, size_t ws_size,
                              hipStream_t stream) {
    const float* q  = (const float*)d_in[0];
    const float* kc = (const float*)d_in[1];
    const float* vc = (const float*)d_in[2];
    const int*   bt = (const int*)d_in[3];
    const int*   cl = (const int*)d_in[4];
    float* out = (float*)d_out;

    paged_attn_kernel<<<dim3(BATCH * NH), dim3(256), 0, stream>>>(q, kc, vc, bt, cl, out);
}